// Round 5
// baseline (84.510 us; speedup 1.0000x reference)
//
#include <hip/hip_runtime.h>

#define NB 8
#define NPTS 4096
#define IPT 4                       // a-points per thread (2 float2 pairs)
#define NPAIR (IPT / 2)
#define OUT_SCALE (1.0f / (float)(NPTS * NB))

typedef float v2f __attribute__((ext_vector_type(2)));

#if defined(__has_builtin) && __has_builtin(__builtin_elementwise_fma)
#define V2FMA(a, b, c) __builtin_elementwise_fma((a), (b), (c))
#else
static __device__ inline v2f V2FMA(v2f a, v2f b, v2f c) {
    v2f r; r.x = fmaf(a.x, b.x, c.x); r.y = fmaf(a.y, b.y, c.y); return r;
}
#endif
#if defined(__has_builtin) && __has_builtin(__builtin_elementwise_min)
#define V2MIN(a, b) __builtin_elementwise_min((a), (b))
#else
static __device__ inline v2f V2MIN(v2f a, v2f b) {
    v2f r; r.x = fminf(a.x, b.x); r.y = fminf(a.y, b.y); return r;
}
#endif

// ---------------- main: grid (NPTS/(256*IPT), NB, 2*CH), block 256, 8 waves/SIMD ----------------
// LDS per m (splatted, 32B, 16B-aligned): {-2bx}x2,{-2by}x2,{-2bz}x2,{||b||^2}x2
// d(a,b) = ||a||^2 + [ ||b||^2 - 2 a.b ]; loop minimizes the bracket, ||a||^2 added in epilogue.
template <int CH_>
__global__ __launch_bounds__(256, 8) void chamfer_main(
    const float* __restrict__ x, const float* __restrict__ y,
    float* __restrict__ pmin, float* __restrict__ out) {
    constexpr int MCHUNK = NPTS / CH_;
    __shared__ alignas(16) v2f qs[MCHUNK * 4];

    const int b   = blockIdx.y;
    const int z   = blockIdx.z;          // 0 .. 2*CH-1
    const int dir = z / CH_;
    const int ch  = z % CH_;
    const int tid = threadIdx.x;

    const float* A = (dir == 0) ? x : y;
    const float* B = (dir == 0) ? y : x;

    // d_out is re-poisoned before every call; zero it (reduce runs strictly after main).
    if (blockIdx.x == 0 && b == 0 && z == 0 && tid == 0) out[0] = 0.0f;

    // Stage chunk into LDS, splatted.
    const float* bb = B + (size_t)b * 3 * NPTS + (size_t)ch * MCHUNK;
    for (int t = tid; t < MCHUNK; t += 256) {
        float bxv = bb[t];
        float byv = bb[NPTS + t];
        float bzv = bb[2 * NPTS + t];
        float w = bxv * bxv + byv * byv + bzv * bzv;
        qs[4 * t + 0] = v2f{-2.0f * bxv, -2.0f * bxv};
        qs[4 * t + 1] = v2f{-2.0f * byv, -2.0f * byv};
        qs[4 * t + 2] = v2f{-2.0f * bzv, -2.0f * bzv};
        qs[4 * t + 3] = v2f{w, w};
    }

    // Load IPT a-points as NPAIR float2 pairs (coalesced).
    const int i0 = blockIdx.x * (256 * IPT) + tid;
    const float* ab = A + (size_t)b * 3 * NPTS;
    v2f ax2[NPAIR], ay2[NPAIR], az2[NPAIR], xx2[NPAIR], vmin2[NPAIR];
#pragma unroll
    for (int p = 0; p < NPAIR; ++p) {
        int ia = i0 + (2 * p) * 256;
        int ib = i0 + (2 * p + 1) * 256;
        ax2[p] = v2f{ab[ia],            ab[ib]};
        ay2[p] = v2f{ab[NPTS + ia],     ab[NPTS + ib]};
        az2[p] = v2f{ab[2 * NPTS + ia], ab[2 * NPTS + ib]};
        xx2[p] = V2FMA(ax2[p], ax2[p], V2FMA(ay2[p], ay2[p], az2[p] * az2[p]));
        vmin2[p] = v2f{3.4e38f, 3.4e38f};
    }
    __syncthreads();

    // Inner scan: 2 m per iteration; per pair: 6 v_pk_fma_f32 + 2 v_pk_min_f32.
    for (int m = 0; m < MCHUNK; m += 2) {
        v2f cx0 = qs[4 * m + 0], cy0 = qs[4 * m + 1], cz0 = qs[4 * m + 2], cw0 = qs[4 * m + 3];
        v2f cx1 = qs[4 * m + 4], cy1 = qs[4 * m + 5], cz1 = qs[4 * m + 6], cw1 = qs[4 * m + 7];
#pragma unroll
        for (int p = 0; p < NPAIR; ++p) {
            v2f t0 = V2FMA(ax2[p], cx0, cw0);
            t0 = V2FMA(ay2[p], cy0, t0);
            t0 = V2FMA(az2[p], cz0, t0);
            v2f t1 = V2FMA(ax2[p], cx1, cw1);
            t1 = V2FMA(ay2[p], cy1, t1);
            t1 = V2FMA(az2[p], cz1, t1);
            vmin2[p] = V2MIN(vmin2[p], V2MIN(t0, t1));
        }
    }

    // Epilogue: add ||a||^2, write partial mins (coalesced in i).
    float* pout = pmin + ((size_t)(dir * NB + b) * CH_ + ch) * NPTS;
#pragma unroll
    for (int p = 0; p < NPAIR; ++p) {
        v2f r = vmin2[p] + xx2[p];
        pout[i0 + (2 * p) * 256]     = r.x;
        pout[i0 + (2 * p + 1) * 256] = r.y;
    }
}

// ---------------- reduce: min over CH chunks, sum all, one atomic/block ----------------
template <int CH_>
__global__ __launch_bounds__(256) void chamfer_reduce(
    const float* __restrict__ pmin, float* __restrict__ out) {
    __shared__ float sred[4];
    const int u  = blockIdx.x * 256 + threadIdx.x;     // 0 .. 2*NB*NPTS-1
    const int i  = u & (NPTS - 1);
    const int db = u >> 12;                            // dir*NB+b
    const float* base = pmin + (size_t)db * CH_ * NPTS + i;
    float vm = base[0];
#pragma unroll
    for (int c = 1; c < CH_; ++c) vm = fminf(vm, base[(size_t)c * NPTS]);

    float s = vm;
#pragma unroll
    for (int off = 32; off > 0; off >>= 1) s += __shfl_down(s, off, 64);
    const int lane = threadIdx.x & 63;
    const int wid  = threadIdx.x >> 6;
    if (lane == 0) sred[wid] = s;
    __syncthreads();
    if (threadIdx.x == 0) {
        float tot = sred[0] + sred[1] + sred[2] + sred[3];
        atomicAdd(out, tot * OUT_SCALE);
    }
}

// ---------------- fallback (tiny ws): slow but correct ----------------
__global__ void zero_out(float* out) { out[0] = 0.0f; }

__global__ __launch_bounds__(256) void chamfer_direct(
    const float* __restrict__ x, const float* __restrict__ y,
    float* __restrict__ out) {
    const int b   = blockIdx.y;
    const int dir = blockIdx.z;
    const float* A  = (dir == 0) ? x : y;
    const float* Bm = (dir == 0) ? y : x;
    const int i = blockIdx.x * blockDim.x + threadIdx.x;
    const float* abase = A + (size_t)b * 3 * NPTS + i;
    const float ax = abase[0], ay = abase[NPTS], az = abase[2 * NPTS];
    const float* bbase = Bm + (size_t)b * 3 * NPTS;
    float vmin = 3.4e38f;
#pragma unroll 8
    for (int m = 0; m < NPTS; ++m) {
        float dx = ax - bbase[m];
        float dy = ay - bbase[NPTS + m];
        float dz = az - bbase[2 * NPTS + m];
        float t = dx * dx;
        t = fmaf(dy, dy, t);
        t = fmaf(dz, dz, t);
        vmin = fminf(vmin, t);
    }
    float s = vmin;
#pragma unroll
    for (int off = 32; off > 0; off >>= 1) s += __shfl_down(s, off, 64);
    if ((threadIdx.x & 63) == 0) atomicAdd(out, s * OUT_SCALE);
}

extern "C" void kernel_launch(void* const* d_in, const int* in_sizes, int n_in,
                              void* d_out, int out_size, void* d_ws, size_t ws_size,
                              hipStream_t stream) {
    const float* x = (const float*)d_in[0];
    const float* y = (const float*)d_in[1];
    float* out  = (float*)d_out;
    float* pmin = (float*)d_ws;

    const dim3 blk(256);
    const int gx = NPTS / (256 * IPT);                     // 4

    const size_t need32 = 2ull * NB * 32 * NPTS * sizeof(float);   // 8 MiB
    const size_t need8  = 2ull * NB * 8  * NPTS * sizeof(float);   // 2 MiB

    if (ws_size >= need32) {
        chamfer_main<32><<<dim3(gx, NB, 2 * 32), blk, 0, stream>>>(x, y, pmin, out);
        chamfer_reduce<32><<<dim3((2 * NB * NPTS) / 256), blk, 0, stream>>>(pmin, out);
    } else if (ws_size >= need8) {
        chamfer_main<8><<<dim3(gx, NB, 2 * 8), blk, 0, stream>>>(x, y, pmin, out);
        chamfer_reduce<8><<<dim3((2 * NB * NPTS) / 256), blk, 0, stream>>>(pmin, out);
    } else {
        zero_out<<<dim3(1), dim3(1), 0, stream>>>(out);
        chamfer_direct<<<dim3(NPTS / 256, NB, 2), blk, 0, stream>>>(x, y, out);
    }
}

// Round 6
// 82.299 us; speedup vs baseline: 1.0269x; 1.0269x over previous
//
#include <hip/hip_runtime.h>

#define NB 8
#define NPTS 4096
#define IPT 8                       // a-points per thread (4 float2 pairs)
#define NPAIR (IPT / 2)
#define OUT_SCALE (1.0f / (float)(NPTS * NB))

typedef float v2f __attribute__((ext_vector_type(2)));

#if defined(__has_builtin) && __has_builtin(__builtin_elementwise_fma)
#define V2FMA(a, b, c) __builtin_elementwise_fma((a), (b), (c))
#else
static __device__ inline v2f V2FMA(v2f a, v2f b, v2f c) {
    v2f r; r.x = fmaf(a.x, b.x, c.x); r.y = fmaf(a.y, b.y, c.y); return r;
}
#endif
#if defined(__has_builtin) && __has_builtin(__builtin_elementwise_min)
#define V2MIN(a, b) __builtin_elementwise_min((a), (b))
#else
static __device__ inline v2f V2MIN(v2f a, v2f b) {
    v2f r; r.x = fminf(a.x, b.x); r.y = fminf(a.y, b.y); return r;
}
#endif

static __device__ inline v2f splat2(float s) { v2f r; r.x = s; r.y = s; return r; }

// ---------------- main: grid (NPTS/(256*IPT), NB, 2*CH), block 256 ----------------
// LDS per m (UNsplatted, 16B): {-2bx, -2by, -2bz, ||b||^2} -> 1 ds_read_b128 per m broadcast.
// Splat to v2f in registers (op_sel / cheap movs). d(a,b) = ||a||^2 + [||b||^2 - 2 a.b];
// the loop minimizes the bracket, ||a||^2 added in epilogue.
template <int CH_>
__global__ __launch_bounds__(256) void chamfer_main(
    const float* __restrict__ x, const float* __restrict__ y,
    float* __restrict__ pmin, float* __restrict__ out) {
    constexpr int MCHUNK = NPTS / CH_;
    __shared__ alignas(16) float4 qs[MCHUNK];

    const int b   = blockIdx.y;
    const int z   = blockIdx.z;          // 0 .. 2*CH-1
    const int dir = z / CH_;
    const int ch  = z % CH_;
    const int tid = threadIdx.x;

    const float* A = (dir == 0) ? x : y;
    const float* B = (dir == 0) ? y : x;

    // out is re-poisoned before every call; zero it (reduce runs strictly after main).
    if (blockIdx.x == 0 && b == 0 && z == 0 && tid == 0) out[0] = 0.0f;

    // Stage chunk into LDS (coalesced global reads, 16B rows).
    const float* bb = B + (size_t)b * 3 * NPTS + (size_t)ch * MCHUNK;
    for (int t = tid; t < MCHUNK; t += 256) {
        float bxv = bb[t];
        float byv = bb[NPTS + t];
        float bzv = bb[2 * NPTS + t];
        qs[t] = make_float4(-2.0f * bxv, -2.0f * byv, -2.0f * bzv,
                            bxv * bxv + byv * byv + bzv * bzv);
    }

    // Load IPT a-points as NPAIR float2 pairs (coalesced).
    const int i0 = blockIdx.x * (256 * IPT) + tid;
    const float* ab = A + (size_t)b * 3 * NPTS;
    v2f ax2[NPAIR], ay2[NPAIR], az2[NPAIR], xx2[NPAIR], vmin2[NPAIR];
#pragma unroll
    for (int p = 0; p < NPAIR; ++p) {
        int ia = i0 + (2 * p) * 256;
        int ib = i0 + (2 * p + 1) * 256;
        ax2[p] = v2f{ab[ia],            ab[ib]};
        ay2[p] = v2f{ab[NPTS + ia],     ab[NPTS + ib]};
        az2[p] = v2f{ab[2 * NPTS + ia], ab[2 * NPTS + ib]};
        xx2[p] = V2FMA(ax2[p], ax2[p], V2FMA(ay2[p], ay2[p], az2[p] * az2[p]));
        vmin2[p] = v2f{3.4e38f, 3.4e38f};
    }
    __syncthreads();

    // Inner scan: 2 m per iteration; 2 ds_read_b128 broadcasts + register splats + pk math.
    for (int m = 0; m < MCHUNK; m += 2) {
        float4 c0 = qs[m];
        float4 c1 = qs[m + 1];
        v2f cx0 = splat2(c0.x), cy0 = splat2(c0.y), cz0 = splat2(c0.z), cw0 = splat2(c0.w);
        v2f cx1 = splat2(c1.x), cy1 = splat2(c1.y), cz1 = splat2(c1.z), cw1 = splat2(c1.w);
#pragma unroll
        for (int p = 0; p < NPAIR; ++p) {
            v2f t0 = V2FMA(ax2[p], cx0, cw0);
            t0 = V2FMA(ay2[p], cy0, t0);
            t0 = V2FMA(az2[p], cz0, t0);
            v2f t1 = V2FMA(ax2[p], cx1, cw1);
            t1 = V2FMA(ay2[p], cy1, t1);
            t1 = V2FMA(az2[p], cz1, t1);
            vmin2[p] = V2MIN(vmin2[p], V2MIN(t0, t1));
        }
    }

    // Epilogue: add ||a||^2, write partial mins (coalesced in i).
    float* pout = pmin + ((size_t)(dir * NB + b) * CH_ + ch) * NPTS;
#pragma unroll
    for (int p = 0; p < NPAIR; ++p) {
        v2f r = vmin2[p] + xx2[p];
        pout[i0 + (2 * p) * 256]     = r.x;
        pout[i0 + (2 * p + 1) * 256] = r.y;
    }
}

// ---------------- reduce: min over CH chunks, sum all, one atomic/block ----------------
template <int CH_>
__global__ __launch_bounds__(256) void chamfer_reduce(
    const float* __restrict__ pmin, float* __restrict__ out) {
    __shared__ float sred[4];
    const int u  = blockIdx.x * 256 + threadIdx.x;     // 0 .. 2*NB*NPTS-1
    const int i  = u & (NPTS - 1);
    const int db = u >> 12;                            // dir*NB+b
    const float* base = pmin + (size_t)db * CH_ * NPTS + i;
    float vm = base[0];
#pragma unroll
    for (int c = 1; c < CH_; ++c) vm = fminf(vm, base[(size_t)c * NPTS]);

    float s = vm;
#pragma unroll
    for (int off = 32; off > 0; off >>= 1) s += __shfl_down(s, off, 64);
    const int lane = threadIdx.x & 63;
    const int wid  = threadIdx.x >> 6;
    if (lane == 0) sred[wid] = s;
    __syncthreads();
    if (threadIdx.x == 0) {
        float tot = sred[0] + sred[1] + sred[2] + sred[3];
        atomicAdd(out, tot * OUT_SCALE);
    }
}

// ---------------- fallback (tiny ws): slow but correct ----------------
__global__ void zero_out(float* out) { out[0] = 0.0f; }

__global__ __launch_bounds__(256) void chamfer_direct(
    const float* __restrict__ x, const float* __restrict__ y,
    float* __restrict__ out) {
    const int b   = blockIdx.y;
    const int dir = blockIdx.z;
    const float* A  = (dir == 0) ? x : y;
    const float* Bm = (dir == 0) ? y : x;
    const int i = blockIdx.x * blockDim.x + threadIdx.x;
    const float* abase = A + (size_t)b * 3 * NPTS + i;
    const float ax = abase[0], ay = abase[NPTS], az = abase[2 * NPTS];
    const float* bbase = Bm + (size_t)b * 3 * NPTS;
    float vmin = 3.4e38f;
#pragma unroll 8
    for (int m = 0; m < NPTS; ++m) {
        float dx = ax - bbase[m];
        float dy = ay - bbase[NPTS + m];
        float dz = az - bbase[2 * NPTS + m];
        float t = dx * dx;
        t = fmaf(dy, dy, t);
        t = fmaf(dz, dz, t);
        vmin = fminf(vmin, t);
    }
    float s = vmin;
#pragma unroll
    for (int off = 32; off > 0; off >>= 1) s += __shfl_down(s, off, 64);
    if ((threadIdx.x & 63) == 0) atomicAdd(out, s * OUT_SCALE);
}

extern "C" void kernel_launch(void* const* d_in, const int* in_sizes, int n_in,
                              void* d_out, int out_size, void* d_ws, size_t ws_size,
                              hipStream_t stream) {
    const float* x = (const float*)d_in[0];
    const float* y = (const float*)d_in[1];
    float* out  = (float*)d_out;
    float* pmin = (float*)d_ws;

    const dim3 blk(256);
    const int gx = NPTS / (256 * IPT);                     // 2

    const size_t need32 = 2ull * NB * 32 * NPTS * sizeof(float);   // 8 MiB
    const size_t need8  = 2ull * NB * 8  * NPTS * sizeof(float);   // 2 MiB

    if (ws_size >= need32) {
        chamfer_main<32><<<dim3(gx, NB, 2 * 32), blk, 0, stream>>>(x, y, pmin, out);
        chamfer_reduce<32><<<dim3((2 * NB * NPTS) / 256), blk, 0, stream>>>(pmin, out);
    } else if (ws_size >= need8) {
        chamfer_main<8><<<dim3(gx, NB, 2 * 8), blk, 0, stream>>>(x, y, pmin, out);
        chamfer_reduce<8><<<dim3((2 * NB * NPTS) / 256), blk, 0, stream>>>(pmin, out);
    } else {
        zero_out<<<dim3(1), dim3(1), 0, stream>>>(out);
        chamfer_direct<<<dim3(NPTS / 256, NB, 2), blk, 0, stream>>>(x, y, out);
    }
}